// Round 3
// baseline (16.049 us; speedup 1.0000x reference)
//
#include <hip/hip_runtime.h>
#include <math.h>

constexpr int NV  = 10;   // n_vars
constexpr int NB  = 5;    // n_basis = 1 + 2*K_MAX
constexpr int DD  = 32;   // D
constexpr int BLK = 256;

#define CONST_AS __attribute__((address_space(4)))
// Generic->constant addrspace cast (composable_kernel idiom): makes the
// backend emit s_load (SMEM/scalar pipe) for wave-uniform reads.
__device__ __forceinline__ const CONST_AS float* cptr(const float* p) {
    return (const CONST_AS float*)(unsigned long long)p;
}

__global__ __launch_bounds__(BLK) void nxro_fused(
    const float* __restrict__ x,   // [B,10]
    const float* __restrict__ t,   // [B]
    const float* __restrict__ L,   // [5,10,10]
    const float* __restrict__ wq,  // [32]
    const float* __restrict__ wk,  // [32]
    const float* __restrict__ wv,  // [32]
    const float* __restrict__ wo,  // [32]
    const float* __restrict__ aw,  // [5]
    float* __restrict__ out,       // [B,10]
    int B)
{
    __shared__ float4 sstage4[BLK * NV / 4];  // 2560 floats = 10240 B
    float* sstage = reinterpret_cast<float*>(sstage4);

    const int tid = threadIdx.x;
    const long long base  = (long long)blockIdx.x * BLK;
    const long long nelem = (long long)B * NV;

    // Uniform scalars via the scalar pipe (redundant per thread, all-SGPR data)
    const CONST_AS float* Lc  = cptr(L);
    const CONST_AS float* wqc = cptr(wq);
    const CONST_AS float* wkc = cptr(wk);
    const CONST_AS float* wvc = cptr(wv);
    const CONST_AS float* woc = cptr(wo);
    const CONST_AS float* awc = cptr(aw);

    float qk = 0.f, vo = 0.f;
    #pragma unroll
    for (int d = 0; d < DD; ++d) {
        qk = fmaf(wqc[d], wkc[d], qk);
        vo = fmaf(wvc[d], woc[d], vo);
    }
    const float c = qk * 0.17677669529663687f;  // (wq.wk)/sqrt(32)
    const float g = vo;                          // wv.wo

    // ---- coalesced float4 load of this block's x rows into LDS ----
    {
        const float4* xg = reinterpret_cast<const float4*>(x + base * NV);
        const long long n4 = (nelem - base * NV) / 4;
        #pragma unroll
        for (int i = tid; i < BLK * NV / 4; i += BLK)
            sstage4[i] = (i < n4) ? xg[i] : make_float4(0.f, 0.f, 0.f, 0.f);
    }
    __syncthreads();

    const long long b = base + tid;
    const bool active = (b < (long long)B);
    if (active) {
        float xv[NV];
        #pragma unroll
        for (int v = 0; v < NV; ++v) xv[v] = sstage[tid * NV + v];
        const float tt = t[b];

        // Fourier embedding via HW sin/cos (input in REVOLUTIONS):
        // emb = [1, cos(2pi t), sin(2pi t), cos(4pi t), sin(4pi t)]
        const float t2 = tt + tt;
        const float emb[NB] = {
            1.f,
            __builtin_amdgcn_cosf(tt),
            __builtin_amdgcn_sinf(tt),
            __builtin_amdgcn_cosf(t2),
            __builtin_amdgcn_sinf(t2)
        };

        // dxdt[u] = sum_k emb[k] * (L_k x)[u]; L via s_load (SGPR operand)
        float dxdt[NV];
        #pragma unroll
        for (int u = 0; u < NV; ++u) dxdt[u] = 0.f;
        #pragma unroll
        for (int k = 0; k < NB; ++k) {
            const float ek = emb[k];
            #pragma unroll
            for (int u = 0; u < NV; ++u) {
                const CONST_AS float* Lr = Lc + (k * NV + u) * NV;
                float acc = Lr[0] * xv[0];
                #pragma unroll
                for (int v = 1; v < NV; ++v)
                    acc = fmaf(Lr[v], xv[v], acc);
                dxdt[u] = fmaf(ek, acc, dxdt[u]);
            }
        }

        // alpha = sigmoid(emb . alpha_w)
        float z = 0.f;
        #pragma unroll
        for (int k = 0; k < NB; ++k) z = fmaf(emb[k], awc[k], z);
        const float alpha = 1.f / (1.f + __expf(-z));
        const float ga = g * alpha;

        // masked attention: row v attends to {0, 1, v} (v<2: {0,1})
        const float x0 = xv[0], x1 = xv[1];
        float res[NV];
        #pragma unroll
        for (int v = 0; v < NV; ++v) {
            const float s0 = xv[v] * x0 * c;
            const float s1 = xv[v] * x1 * c;
            float w;
            if (v < 2) {
                const float m = fmaxf(s0, s1);
                const float e0 = __expf(s0 - m), e1 = __expf(s1 - m);
                w = fmaf(e0, x0, e1 * x1) / (e0 + e1);
            } else {
                const float sv = xv[v] * xv[v] * c;
                const float m = fmaxf(fmaxf(s0, s1), sv);
                const float e0 = __expf(s0 - m), e1 = __expf(s1 - m),
                            ev = __expf(sv - m);
                w = fmaf(e0, x0, fmaf(e1, x1, ev * xv[v])) / (e0 + e1 + ev);
            }
            res[v] = fmaf(w, ga, dxdt[v]);
        }
        // own-row write-back (no cross-thread hazard vs own-row reads above)
        #pragma unroll
        for (int v = 0; v < NV; ++v) sstage[tid * NV + v] = res[v];
    }
    __syncthreads();

    // ---- coalesced float4 store ----
    {
        float4* og = reinterpret_cast<float4*>(out + base * NV);
        const long long n4 = (nelem - base * NV) / 4;
        #pragma unroll
        for (int i = tid; i < BLK * NV / 4; i += BLK)
            if (i < n4) og[i] = sstage4[i];
    }
}

extern "C" void kernel_launch(void* const* d_in, const int* in_sizes, int n_in,
                              void* d_out, int out_size, void* d_ws, size_t ws_size,
                              hipStream_t stream) {
    const float* x  = (const float*)d_in[0];
    const float* t  = (const float*)d_in[1];
    const float* L  = (const float*)d_in[2];
    const float* wq = (const float*)d_in[3];
    const float* wk = (const float*)d_in[4];
    const float* wv = (const float*)d_in[5];
    const float* wo = (const float*)d_in[6];
    const float* aw = (const float*)d_in[7];
    float* out = (float*)d_out;
    const int B = in_sizes[1];  // t_years element count

    const int grid = (B + BLK - 1) / BLK;
    nxro_fused<<<grid, BLK, 0, stream>>>(x, t, L, wq, wk, wv, wo, aw, out, B);
}

// Round 4
// 13.579 us; speedup vs baseline: 1.1819x; 1.1819x over previous
//
#include <hip/hip_runtime.h>
#include <math.h>

constexpr int NV  = 10;   // n_vars
constexpr int NB  = 5;    // n_basis
constexpr int BLK = 256;

#define CONST_AS __attribute__((address_space(4)))
__device__ __forceinline__ const CONST_AS float* cptr(const float* p) {
    return (const CONST_AS float*)(unsigned long long)p;
}

__global__ __launch_bounds__(BLK) void nxro_fused(
    const float* __restrict__ x,   // [B,10]
    const float* __restrict__ t,   // [B]
    const float* __restrict__ L,   // [5,10,10] = float4[125]
    const float* __restrict__ wq,  // [32]
    const float* __restrict__ wk,  // [32]
    const float* __restrict__ wv,  // [32]
    const float* __restrict__ wo,  // [32]
    const float* __restrict__ aw,  // [5]
    float* __restrict__ out,       // [B,10]
    int B)
{
    const int tid  = threadIdx.x;
    const int lane = tid & 63;

    // ---- per-wave c,g: lane-split dot products + butterfly reduce ----
    // lanes 0..31: wq.wk ; lanes 32..63: wv.wo  (all lanes active here)
    float pa, pb;
    if (lane < 32) { pa = wq[lane];      pb = wk[lane];      }
    else           { pa = wv[lane - 32]; pb = wo[lane - 32]; }
    float dotv = pa * pb;
    #pragma unroll
    for (int m = 16; m >= 1; m >>= 1)
        dotv += __shfl_xor(dotv, m, 64);
    const float c = __shfl(dotv, 0, 64) * 0.17677669529663687f; // (wq.wk)/sqrt(32)
    const float g = __shfl(dotv, 32, 64);                        // wv.wo

    const long long b = (long long)blockIdx.x * BLK + tid;
    if (b >= (long long)B) return;

    // ---- t first: start the sin/cos chain early ----
    const float tt = t[b];
    const float t2 = tt + tt;
    // HW sin/cos take REVOLUTIONS; t in [0,1), 2t in [0,2) — in range.
    const float emb1 = __builtin_amdgcn_cosf(tt);
    const float emb2 = __builtin_amdgcn_sinf(tt);
    const float emb3 = __builtin_amdgcn_cosf(t2);
    const float emb4 = __builtin_amdgcn_sinf(t2);

    // ---- x row: 5x float2 (row stride 40B -> 8B aligned) ----
    float xv[NV];
    {
        const float2* xr = reinterpret_cast<const float2*>(x + b * NV);
        #pragma unroll
        for (int i = 0; i < 5; ++i) {
            const float2 p = xr[i];
            xv[2 * i] = p.x; xv[2 * i + 1] = p.y;
        }
    }

    // ---- z factorization: z[k*10+v] = emb[k]*xv[v]; k=0 row is xv itself ----
    float zz[NB - 1][NV];
    #pragma unroll
    for (int v = 0; v < NV; ++v) {
        zz[0][v] = emb1 * xv[v];
        zz[1][v] = emb2 * xv[v];
        zz[2][v] = emb3 * xv[v];
        zz[3][v] = emb4 * xv[v];
    }

    // ---- dxdt[u] = sum_e L[e] * z[(k,v)(e)] over flat float4 L ----
    float dxdt[NV];
    #pragma unroll
    for (int u = 0; u < NV; ++u) dxdt[u] = 0.f;
    {
        const float4* __restrict__ L4 = reinterpret_cast<const float4*>(L);
        #pragma unroll
        for (int f = 0; f < 125; ++f) {
            const float4 q = L4[f];
            #pragma unroll
            for (int cc = 0; cc < 4; ++cc) {
                const int e = 4 * f + cc;                 // compile-time
                const int k = e / 100;
                const int u = (e / 10) % 10;
                const int v = e % 10;
                const float qc = (cc == 0) ? q.x : (cc == 1) ? q.y
                               : (cc == 2) ? q.z : q.w;
                const float zj = (k == 0) ? xv[v] : zz[k - 1][v];
                dxdt[u] = fmaf(qc, zj, dxdt[u]);
            }
        }
    }

    // ---- alpha = sigmoid(emb . alpha_w)  (aw via scalar pipe, 5 dwords) ----
    const CONST_AS float* awc = cptr(aw);
    float zs = awc[0];
    zs = fmaf(emb1, awc[1], zs);
    zs = fmaf(emb2, awc[2], zs);
    zs = fmaf(emb3, awc[3], zs);
    zs = fmaf(emb4, awc[4], zs);
    const float alpha = __builtin_amdgcn_rcpf(1.f + __expf(-zs));
    const float ga = g * alpha;

    // ---- masked attention: row v attends to {0,1,v} (v<2: {0,1}) ----
    const float x0 = xv[0], x1 = xv[1];
    float res[NV];
    #pragma unroll
    for (int v = 0; v < NV; ++v) {
        const float s0 = xv[v] * x0 * c;
        const float s1 = xv[v] * x1 * c;
        float w;
        if (v < 2) {
            const float m = fmaxf(s0, s1);
            const float e0 = __expf(s0 - m), e1 = __expf(s1 - m);
            w = fmaf(e0, x0, e1 * x1) * __builtin_amdgcn_rcpf(e0 + e1);
        } else {
            const float sv = xv[v] * xv[v] * c;
            const float m = fmaxf(fmaxf(s0, s1), sv);
            const float e0 = __expf(s0 - m), e1 = __expf(s1 - m),
                        ev = __expf(sv - m);
            w = fmaf(e0, x0, fmaf(e1, x1, ev * xv[v]))
                * __builtin_amdgcn_rcpf(e0 + e1 + ev);
        }
        res[v] = fmaf(w, ga, dxdt[v]);
    }

    // ---- direct store: 5x float2 ----
    {
        float2* orow = reinterpret_cast<float2*>(out + b * NV);
        #pragma unroll
        for (int i = 0; i < 5; ++i)
            orow[i] = make_float2(res[2 * i], res[2 * i + 1]);
    }
}

extern "C" void kernel_launch(void* const* d_in, const int* in_sizes, int n_in,
                              void* d_out, int out_size, void* d_ws, size_t ws_size,
                              hipStream_t stream) {
    const float* x  = (const float*)d_in[0];
    const float* t  = (const float*)d_in[1];
    const float* L  = (const float*)d_in[2];
    const float* wq = (const float*)d_in[3];
    const float* wk = (const float*)d_in[4];
    const float* wv = (const float*)d_in[5];
    const float* wo = (const float*)d_in[6];
    const float* aw = (const float*)d_in[7];
    float* out = (float*)d_out;
    const int B = in_sizes[1];  // t_years element count

    const int grid = (B + BLK - 1) / BLK;
    nxro_fused<<<grid, BLK, 0, stream>>>(x, t, L, wq, wk, wv, wo, aw, out, B);
}